// Round 1
// baseline (424.825 us; speedup 1.0000x reference)
//
#include <hip/hip_runtime.h>

typedef __attribute__((ext_vector_type(4))) float  f32x4;
typedef __attribute__((ext_vector_type(8))) short  bf8;     // 8 bf16 raw bits
typedef __attribute__((ext_vector_type(4))) unsigned short us4;

#define AS1 __attribute__((address_space(1)))
#define AS3 __attribute__((address_space(3)))

static __device__ __forceinline__ unsigned short f2b(float f) {
  unsigned u = __builtin_bit_cast(unsigned, f);
  u += 0x7FFFu + ((u >> 16) & 1u);          // RNE
  return (unsigned short)(u >> 16);
}

// ---------------- fp32 -> bf16 conversion ----------------
__global__ __launch_bounds__(256) void cvt_kernel(const float* __restrict__ in,
                                                  unsigned short* __restrict__ out,
                                                  int n) {
  int i = blockIdx.x * 256 + threadIdx.x;
  int idx = i << 2;
  if (idx >= n) return;
  f32x4 v = *(const f32x4*)(in + idx);
  us4 o;
  o[0] = f2b(v[0]); o[1] = f2b(v[1]); o[2] = f2b(v[2]); o[3] = f2b(v[3]);
  *(us4*)(out + idx) = o;
}

// ---------------- GEMM: C[m][n] = sum_k A[m][k] * Bt[n][k] + bias[n] ----------------
// EPI 0: q scatter  (B,T,C)->(B,H,T,d) bf16
// EPI 1: kv scatter (B,S,2C)->k,v (B,H,S,d) bf16
// EPI 2: fp32 out, row-major MxN
template<int EPI>
__global__ __launch_bounds__(256) void gemm_bt(const unsigned short* __restrict__ A,
                                               const unsigned short* __restrict__ Bt,
                                               const float* __restrict__ bias,
                                               unsigned short* __restrict__ out0,
                                               unsigned short* __restrict__ out1,
                                               float* __restrict__ outf,
                                               int M, int N, int K) {
  __shared__ unsigned short As[128 * 32];
  __shared__ unsigned short Bs[128 * 32];
  const int tid = threadIdx.x;
  const int lane = tid & 63, wid = tid >> 6;
  const int l15 = lane & 15, lg = lane >> 4;
  const int bm = blockIdx.y, bn = blockIdx.x;
  const int wr = wid >> 1, wc = wid & 1;       // 2x2 waves of 64x64
  f32x4 acc[4][4] = {};

  const unsigned short* Ab = A  + (size_t)bm * 128 * K;
  const unsigned short* Bb = Bt + (size_t)bn * 128 * K;

  for (int k0 = 0; k0 < K; k0 += 32) {
    __syncthreads();
#pragma unroll
    for (int r = 0; r < 2; ++r) {
      int c = r * 256 + tid;
      int row = c >> 2, c8 = c & 3;            // 4 chunks of 8 bf16 per row
      const unsigned short* ga = Ab + (size_t)row * K + k0 + c8 * 8;
      const unsigned short* gb = Bb + (size_t)row * K + k0 + c8 * 8;
      AS3 unsigned short* la = (AS3 unsigned short*)As + (r * 256 + wid * 64) * 8;
      AS3 unsigned short* lb = (AS3 unsigned short*)Bs + (r * 256 + wid * 64) * 8;
      __builtin_amdgcn_global_load_lds((const AS1 void*)ga, (AS3 void*)la, 16, 0, 0);
      __builtin_amdgcn_global_load_lds((const AS1 void*)gb, (AS3 void*)lb, 16, 0, 0);
    }
    __syncthreads();
    bf8 af[4], bv[4];
#pragma unroll
    for (int m = 0; m < 4; ++m)
      af[m] = *(const bf8*)&As[(wr * 64 + m * 16 + l15) * 32 + lg * 8];
#pragma unroll
    for (int n = 0; n < 4; ++n)
      bv[n] = *(const bf8*)&Bs[(wc * 64 + n * 16 + l15) * 32 + lg * 8];
#pragma unroll
    for (int m = 0; m < 4; ++m)
#pragma unroll
      for (int n = 0; n < 4; ++n)
        acc[m][n] = __builtin_amdgcn_mfma_f32_16x16x32_bf16(af[m], bv[n], acc[m][n], 0, 0, 0);
  }

  float bvs[4];
#pragma unroll
  for (int n = 0; n < 4; ++n) bvs[n] = bias[bn * 128 + wc * 64 + n * 16 + l15];

#pragma unroll
  for (int m = 0; m < 4; ++m) {
    int gm0 = bm * 128 + wr * 64 + m * 16 + lg * 4;
#pragma unroll
    for (int n = 0; n < 4; ++n) {
      int gn = bn * 128 + wc * 64 + n * 16 + l15;
#pragma unroll
      for (int j = 0; j < 4; ++j) {
        float val = acc[m][n][j] + bvs[n];
        int gm = gm0 + j;
        if (EPI == 0) {
          int b = gm >> 10, t = gm & 1023, h = gn >> 6, dd = gn & 63;
          out0[((((size_t)b * 16 + h) << 10) + t) * 64 + dd] = f2b(val);
        } else if (EPI == 1) {
          int b = gm >> 10, s = gm & 1023;
          if (gn < 1024) {
            int h = gn >> 6, dd = gn & 63;
            out0[((((size_t)b * 16 + h) << 10) + s) * 64 + dd] = f2b(val);
          } else {
            int g2 = gn - 1024, h = g2 >> 6, dd = g2 & 63;
            out1[((((size_t)b * 16 + h) << 10) + s) * 64 + dd] = f2b(val);
          }
        } else {
          outf[(size_t)gm * N + gn] = val;
        }
      }
    }
  }
}

// ---------------- flash attention (causal), per-(b,h) 64-row q tiles ----------------
// q,k,v: (B,H,1024,64) bf16; out: (B,T,C) bf16 at [b*T+t][h*64+dd]
__global__ __launch_bounds__(256) void attn_kernel(const unsigned short* __restrict__ q,
                                                   const unsigned short* __restrict__ k,
                                                   const unsigned short* __restrict__ v,
                                                   unsigned short* __restrict__ out) {
  const int qt = blockIdx.x;   // 0..15
  const int bh = blockIdx.y;   // 0..127
  const int tid = threadIdx.x, lane = tid & 63, wid = tid >> 6;
  const int l15 = lane & 15, lg = lane >> 4;
  __shared__ unsigned short Pl[4][16 * 64];
  __shared__ unsigned short Vt[64 * 72];   // transposed V tile, padded stride

  const size_t kvbase = (size_t)bh * 1024 * 64;
  const int q0 = qt * 64;

  bf8 qf[2];
  {
    const unsigned short* qp = q + kvbase + (size_t)(q0 + wid * 16 + l15) * 64;
    qf[0] = *(const bf8*)(qp + lg * 8);
    qf[1] = *(const bf8*)(qp + 32 + lg * 8);
  }
  f32x4 o[4] = {};
  float mrow[4] = {-1e30f, -1e30f, -1e30f, -1e30f};
  float lrow[4] = {0.f, 0.f, 0.f, 0.f};

  for (int st = 0; st <= qt; ++st) {
    const int s0 = st * 64;
    __syncthreads();                       // previous Vt reads done
    // stage V transposed: Vt[dd][s]
#pragma unroll
    for (int r = 0; r < 2; ++r) {
      int c = r * 256 + tid;
      int s = c >> 3, d8 = c & 7;
      bf8 vv = *(const bf8*)(v + kvbase + (size_t)(s0 + s) * 64 + d8 * 8);
#pragma unroll
      for (int i = 0; i < 8; ++i)
        Vt[(d8 * 8 + i) * 72 + s] = (unsigned short)vv[i];
    }
    // QK^T (K read direct from global; B^T[s][dd] = K[s][dd])
    float att[4][4];
#pragma unroll
    for (int n = 0; n < 4; ++n) {
      f32x4 a = {0.f, 0.f, 0.f, 0.f};
      const unsigned short* kp = k + kvbase + (size_t)(s0 + n * 16 + l15) * 64;
      a = __builtin_amdgcn_mfma_f32_16x16x32_bf16(qf[0], *(const bf8*)(kp + lg * 8), a, 0, 0, 0);
      a = __builtin_amdgcn_mfma_f32_16x16x32_bf16(qf[1], *(const bf8*)(kp + 32 + lg * 8), a, 0, 0, 0);
#pragma unroll
      for (int j = 0; j < 4; ++j) att[n][j] = a[j] * 0.125f;
    }
    if (st == qt) {
#pragma unroll
      for (int n = 0; n < 4; ++n)
#pragma unroll
        for (int j = 0; j < 4; ++j)
          if (n * 16 + l15 > wid * 16 + lg * 4 + j) att[n][j] = -1e30f;
    }
    // online softmax (rows owned by lane: rows lg*4+j, reduce over 16 cols via shfl)
    float pm[4], mnew[4], al[4], ps[4];
#pragma unroll
    for (int j = 0; j < 4; ++j)
      pm[j] = fmaxf(fmaxf(att[0][j], att[1][j]), fmaxf(att[2][j], att[3][j]));
#pragma unroll
    for (int sh = 1; sh < 16; sh <<= 1)
#pragma unroll
      for (int j = 0; j < 4; ++j) pm[j] = fmaxf(pm[j], __shfl_xor(pm[j], sh));
#pragma unroll
    for (int j = 0; j < 4; ++j) {
      mnew[j] = fmaxf(mrow[j], pm[j]);
      al[j] = __expf(mrow[j] - mnew[j]);
      ps[j] = 0.f;
    }
#pragma unroll
    for (int n = 0; n < 4; ++n)
#pragma unroll
      for (int j = 0; j < 4; ++j) {
        float p = __expf(att[n][j] - mnew[j]);
        ps[j] += p;
        Pl[wid][(lg * 4 + j) * 64 + n * 16 + l15] = f2b(p);
      }
#pragma unroll
    for (int sh = 1; sh < 16; sh <<= 1)
#pragma unroll
      for (int j = 0; j < 4; ++j) ps[j] += __shfl_xor(ps[j], sh);
#pragma unroll
    for (int j = 0; j < 4; ++j) {
      lrow[j] = lrow[j] * al[j] + ps[j];
      mrow[j] = mnew[j];
    }
#pragma unroll
    for (int n = 0; n < 4; ++n) {
      f32x4 t = o[n];
#pragma unroll
      for (int j = 0; j < 4; ++j) t[j] *= al[j];
      o[n] = t;
    }
    __syncthreads();                        // Vt staged by all waves
    // PV: out[q][dd] += P[q][s] V[s][dd]
#pragma unroll
    for (int n = 0; n < 4; ++n) {
#pragma unroll
      for (int kk = 0; kk < 2; ++kk) {
        bf8 pa = *(const bf8*)&Pl[wid][l15 * 64 + kk * 32 + lg * 8];
        bf8 vb = *(const bf8*)&Vt[(n * 16 + l15) * 72 + kk * 32 + lg * 8];
        o[n] = __builtin_amdgcn_mfma_f32_16x16x32_bf16(pa, vb, o[n], 0, 0, 0);
      }
    }
  }
  // epilogue: out[b*T+t][h*64+dd] bf16
  const int b = bh >> 4, h = bh & 15;
#pragma unroll
  for (int n = 0; n < 4; ++n)
#pragma unroll
    for (int j = 0; j < 4; ++j) {
      float val = o[n][j] / lrow[j];
      int t = q0 + wid * 16 + lg * 4 + j;
      out[((size_t)b * 1024 + t) * 1024 + h * 64 + n * 16 + l15] = f2b(val);
    }
}

extern "C" void kernel_launch(void* const* d_in, const int* in_sizes, int n_in,
                              void* d_out, int out_size, void* d_ws, size_t ws_size,
                              hipStream_t stream) {
  const float* x   = (const float*)d_in[0];
  const float* ft  = (const float*)d_in[1];
  const float* Wc  = (const float*)d_in[2];
  const float* bc  = (const float*)d_in[3];
  const float* Wf  = (const float*)d_in[4];
  const float* bff = (const float*)d_in[5];
  const float* Wp  = (const float*)d_in[6];
  const float* bp  = (const float*)d_in[7];
  float* out = (float*)d_out;

  const size_t MEG = 1024 * 1024;
  unsigned short* xb  = (unsigned short*)d_ws;   // 8M elems
  unsigned short* fb  = xb  + 8 * MEG;           // 8M
  unsigned short* Wcb = fb  + 8 * MEG;           // 1M
  unsigned short* Wfb = Wcb + 1 * MEG;           // 2M
  unsigned short* Wpb = Wfb + 2 * MEG;           // 1M
  unsigned short* qb  = Wpb + 1 * MEG;           // 8M
  unsigned short* kb  = qb  + 8 * MEG;           // 8M
  unsigned short* vb  = kb  + 8 * MEG;           // 8M
  unsigned short* ab  = vb  + 8 * MEG;           // 8M  (total 104MB)

  cvt_kernel<<<8192, 256, 0, stream>>>(x,  xb,  8 * MEG);
  cvt_kernel<<<8192, 256, 0, stream>>>(ft, fb,  8 * MEG);
  cvt_kernel<<<1024, 256, 0, stream>>>(Wc, Wcb, 1 * MEG);
  cvt_kernel<<<2048, 256, 0, stream>>>(Wf, Wfb, 2 * MEG);
  cvt_kernel<<<1024, 256, 0, stream>>>(Wp, Wpb, 1 * MEG);

  gemm_bt<0><<<dim3(8, 64), 256, 0, stream>>>(xb, Wcb, bc, qb, nullptr, nullptr, 8192, 1024, 1024);
  gemm_bt<1><<<dim3(16, 64), 256, 0, stream>>>(fb, Wfb, bff, kb, vb, nullptr, 8192, 2048, 1024);
  attn_kernel<<<dim3(16, 128), 256, 0, stream>>>(qb, kb, vb, ab);
  gemm_bt<2><<<dim3(8, 64), 256, 0, stream>>>(ab, Wpb, bp, nullptr, nullptr, out, 8192, 1024, 1024);
}